// Round 5
// baseline (111.779 us; speedup 1.0000x reference)
//
#include <hip/hip_runtime.h>
#include <math.h>

typedef float f32x4 __attribute__((ext_vector_type(4)));

// ---------------------------------------------------------------------------
// Kernel 1: per-camera precompute. cams[c*16] = {R[9], t[3], pad[4]}
// 64 B per camera -> every gather touches exactly one 64B-aligned line.
// ---------------------------------------------------------------------------
__global__ void cam_precompute(const float* __restrict__ params,
                               float* __restrict__ cams, int size) {
    int c = blockIdx.x * blockDim.x + threadIdx.x;
    if (c >= size) return;
    float a  = params[6 * c + 0];
    float b  = params[6 * c + 1];
    float cc = params[6 * c + 2];
    float t2 = a * a + b * b + cc * cc;
    float t  = sqrtf(t2);
    float sin_c, cos_c;
    if (t < 1e-8f) {
        sin_c = 1.0f;
        cos_c = 0.5f;
    } else {
        sin_c = sinf(t) / t;
        cos_c = (1.0f - cosf(t)) / t2;
    }
    float sa = sin_c * a, sb = sin_c * b, sc = sin_c * cc;
    float cab = cos_c * a * b, cac = cos_c * a * cc, cbc = cos_c * b * cc;

    float* o = cams + 16 * c;
    // R = I + sin_c*K + cos_c*K*K,  K = [[0,a,b],[-a,0,c],[-b,-c,0]]
    o[0] = 1.0f - cos_c * (a * a + b * b);
    o[1] =  sa - cbc;
    o[2] =  sb + cac;
    o[3] = -sa - cbc;
    o[4] = 1.0f - cos_c * (a * a + cc * cc);
    o[5] =  sc - cab;
    o[6] = -sb + cac;
    o[7] = -sc - cab;
    o[8] = 1.0f - cos_c * (b * b + cc * cc);
    o[9]  = params[6 * c + 3];
    o[10] = params[6 * c + 4];
    o[11] = params[6 * c + 5];
}

// ---------------------------------------------------------------------------
// Kernel 2: 512-point tile per 256-thread block, 2 points/thread.
// 18 KB LDS arena -> 8 blocks/CU (32 waves/CU, HW max) for cross-phase
// overlap. All global traffic lane-contiguous; LDS transpose arena;
// stride-3 / stride-9 LDS access coprime to 32 banks (conflict-free).
// out layout (floats): [new_o: 3N][new_d: 3N][trans: 3N][R: 9N]
// ---------------------------------------------------------------------------
__launch_bounds__(256, 8)
__global__ void cam_apply(const int* __restrict__ idx,
                          const float* __restrict__ of,
                          const float* __restrict__ df,
                          const f32x4* __restrict__ cams4,
                          float* __restrict__ out,
                          long long N) {
    __shared__ float lds[4608];   // 18 KB arena
    const int tid = threadIdx.x;
    const long long tileBase = (long long)blockIdx.x * 512;

    if (tileBase + 512 <= N) {
        // ---- P1: stage o, d tiles into LDS (dense f32x4 loads) ----
        const f32x4* o4 = (const f32x4*)(of + 3 * tileBase);   // 384 f32x4
        const f32x4* d4 = (const f32x4*)(df + 3 * tileBase);
        f32x4* A = (f32x4*)lds;              // o tile: floats [0, 1536)
        f32x4* B = (f32x4*)(lds + 1536);     // d tile: floats [1536, 3072)
        A[tid] = o4[tid];
        B[tid] = d4[tid];
        if (tid < 128) {
            A[256 + tid] = o4[256 + tid];
            B[256 + tid] = d4[256 + tid];
        }
        int id0 = idx[tileBase + tid];
        int id1 = idx[tileBase + tid + 256];
        __syncthreads();

        // ---- P2: compute 2 points/thread (n = tid, tid+256) ----
        float no[6], nd[6];
        f32x4 c0[2], c1[2], c2[2];
#pragma unroll
        for (int k = 0; k < 2; ++k) {
            int n = tid + 256 * k;
            float ox = lds[3 * n + 0], oy = lds[3 * n + 1], oz = lds[3 * n + 2];
            float dx = lds[1536 + 3 * n + 0], dy = lds[1536 + 3 * n + 1],
                  dz = lds[1536 + 3 * n + 2];
            const f32x4* cp = cams4 + 4 * (long long)(k ? id1 : id0);
            c0[k] = cp[0]; c1[k] = cp[1]; c2[k] = cp[2];

            no[3 * k + 0] = c0[k][0] * ox + c0[k][1] * oy + c0[k][2] * oz + c2[k][1];
            no[3 * k + 1] = c0[k][3] * ox + c1[k][0] * oy + c1[k][1] * oz + c2[k][2];
            no[3 * k + 2] = c1[k][2] * ox + c1[k][3] * oy + c2[k][0] * oz + c2[k][3];

            nd[3 * k + 0] = c0[k][0] * dx + c0[k][1] * dy + c0[k][2] * dz;
            nd[3 * k + 1] = c0[k][3] * dx + c1[k][0] * dy + c1[k][1] * dz;
            nd[3 * k + 2] = c1[k][2] * dx + c1[k][3] * dy + c2[k][0] * dz;
        }
        __syncthreads();   // all o/d reads done; arena reusable

        // ---- P3: no @0, nd @1536, tr @3072 (stride-3, conflict-free) ----
#pragma unroll
        for (int k = 0; k < 2; ++k) {
            int n = tid + 256 * k;
            lds[3 * n + 0] = no[3 * k + 0];
            lds[3 * n + 1] = no[3 * k + 1];
            lds[3 * n + 2] = no[3 * k + 2];
            lds[1536 + 3 * n + 0] = nd[3 * k + 0];
            lds[1536 + 3 * n + 1] = nd[3 * k + 1];
            lds[1536 + 3 * n + 2] = nd[3 * k + 2];
            lds[3072 + 3 * n + 0] = c2[k][1];
            lds[3072 + 3 * n + 1] = c2[k][2];
            lds[3072 + 3 * n + 2] = c2[k][3];
        }
        __syncthreads();

        // ---- P4: dense flush of new_o, new_d, trans (384 f32x4 each) ----
        const f32x4* src = (const f32x4*)lds;
        f32x4* g0 = (f32x4*)(out + 3 * tileBase);
        f32x4* g1 = (f32x4*)(out + 3 * N + 3 * tileBase);
        f32x4* g2 = (f32x4*)(out + 6 * N + 3 * tileBase);
        g0[tid] = src[tid];
        g1[tid] = src[384 + tid];
        g2[tid] = src[768 + tid];
        if (tid < 128) {
            g0[256 + tid] = src[256 + tid];
            g1[256 + tid] = src[640 + tid];
            g2[256 + tid] = src[1024 + tid];
        }
        __syncthreads();   // flush reads done; arena reusable

        // ---- P5: R tile (4608 floats = whole arena), stride-9 ----
#pragma unroll
        for (int k = 0; k < 2; ++k) {
            int n = tid + 256 * k;
            lds[9 * n + 0] = c0[k][0];
            lds[9 * n + 1] = c0[k][1];
            lds[9 * n + 2] = c0[k][2];
            lds[9 * n + 3] = c0[k][3];
            lds[9 * n + 4] = c1[k][0];
            lds[9 * n + 5] = c1[k][1];
            lds[9 * n + 6] = c1[k][2];
            lds[9 * n + 7] = c1[k][3];
            lds[9 * n + 8] = c2[k][0];
        }
        __syncthreads();

        // ---- P6: dense flush of R (1152 f32x4) ----
        f32x4* g3 = (f32x4*)(out + 9 * N + 9 * tileBase);
#pragma unroll
        for (int j = 0; j < 4; ++j) g3[tid + 256 * j] = src[tid + 256 * j];
        if (tid < 128) g3[1024 + tid] = src[1024 + tid];
    } else {
        // ---- tail tile: scalar guarded path ----
        for (int k = 0; k < 2; ++k) {
            long long n = tileBase + tid + 256 * k;
            if (n >= N) continue;
            int cid = idx[n];
            const f32x4* cp = cams4 + 4 * (long long)cid;
            f32x4 c0 = cp[0], c1 = cp[1], c2 = cp[2];
            float ox = of[3 * n + 0], oy = of[3 * n + 1], oz = of[3 * n + 2];
            float dx = df[3 * n + 0], dy = df[3 * n + 1], dz = df[3 * n + 2];

            out[3 * n + 0] = c0[0] * ox + c0[1] * oy + c0[2] * oz + c2[1];
            out[3 * n + 1] = c0[3] * ox + c1[0] * oy + c1[1] * oz + c2[2];
            out[3 * n + 2] = c1[2] * ox + c1[3] * oy + c2[0] * oz + c2[3];

            out[3 * N + 3 * n + 0] = c0[0] * dx + c0[1] * dy + c0[2] * dz;
            out[3 * N + 3 * n + 1] = c0[3] * dx + c1[0] * dy + c1[1] * dz;
            out[3 * N + 3 * n + 2] = c1[2] * dx + c1[3] * dy + c2[0] * dz;

            out[6 * N + 3 * n + 0] = c2[1];
            out[6 * N + 3 * n + 1] = c2[2];
            out[6 * N + 3 * n + 2] = c2[3];

            float Rv[9] = {c0[0], c0[1], c0[2], c0[3], c1[0], c1[1],
                           c1[2], c1[3], c2[0]};
            for (int j = 0; j < 9; ++j) out[9 * N + 9 * n + j] = Rv[j];
        }
    }
}

extern "C" void kernel_launch(void* const* d_in, const int* in_sizes, int n_in,
                              void* d_out, int out_size, void* d_ws, size_t ws_size,
                              hipStream_t stream) {
    const float* params = (const float*)d_in[0];
    const int*   idx    = (const int*)d_in[1];
    const float* o      = (const float*)d_in[2];
    const float* d      = (const float*)d_in[3];
    float*       out    = (float*)d_out;
    float*       cams   = (float*)d_ws;   // size*16 floats (64 KB for size=1000)

    int size = in_sizes[0] / 6;
    long long N = (long long)in_sizes[2] / 3;

    cam_precompute<<<(size + 255) / 256, 256, 0, stream>>>(params, cams, size);

    int blocks = (int)((N + 511) / 512);
    cam_apply<<<blocks, 256, 0, stream>>>(idx, o, d, (const f32x4*)cams,
                                          out, N);
}

// Round 6
// 90.622 us; speedup vs baseline: 1.2335x; 1.2335x over previous
//
#include <hip/hip_runtime.h>
#include <math.h>

typedef float f32x4 __attribute__((ext_vector_type(4)));

// bf16 decode helpers: value stored in low/high 16 bits of a u32 word.
__device__ __forceinline__ float bf_lo(unsigned w) {
    return __uint_as_float(w << 16);
}
__device__ __forceinline__ float bf_hi(unsigned w) {
    return __uint_as_float(w & 0xffff0000u);
}
__device__ __forceinline__ unsigned bf16_rne(float f) {
    unsigned u = __float_as_uint(f);
    return (u + 0x7fffu + ((u >> 16) & 1u)) >> 16;   // round-to-nearest-even
}

// ---------------------------------------------------------------------------
// Kernel 1: per-camera precompute into a 32-byte record (L1-resident table):
//   u32[0..3] = R0..R7 as bf16 pairs (R row-major), u32[4] = R8 (lo half),
//   u32[5..7] = t0,t1,t2 as f32.
// 1000 cams * 32 B = 32 KB -> whole table fits L1; 2 dwordx4 per gather.
// ---------------------------------------------------------------------------
__global__ void cam_precompute(const float* __restrict__ params,
                               unsigned* __restrict__ cams, int size) {
    int c = blockIdx.x * blockDim.x + threadIdx.x;
    if (c >= size) return;
    float a  = params[6 * c + 0];
    float b  = params[6 * c + 1];
    float cc = params[6 * c + 2];
    float t2 = a * a + b * b + cc * cc;
    float t  = sqrtf(t2);
    float sin_c, cos_c;
    if (t < 1e-8f) {
        sin_c = 1.0f;
        cos_c = 0.5f;
    } else {
        sin_c = sinf(t) / t;
        cos_c = (1.0f - cosf(t)) / t2;
    }
    float sa = sin_c * a, sb = sin_c * b, sc = sin_c * cc;
    float cab = cos_c * a * b, cac = cos_c * a * cc, cbc = cos_c * b * cc;

    // R row-major; R = I + sin_c*K + cos_c*K*K, K = [[0,a,b],[-a,0,c],[-b,-c,0]]
    float r0 = 1.0f - cos_c * (a * a + b * b);
    float r1 =  sa - cbc;
    float r2 =  sb + cac;
    float r3 = -sa - cbc;
    float r4 = 1.0f - cos_c * (a * a + cc * cc);
    float r5 =  sc - cab;
    float r6 = -sb + cac;
    float r7 = -sc - cab;
    float r8 = 1.0f - cos_c * (b * b + cc * cc);

    unsigned* o = cams + 8 * c;
    o[0] = bf16_rne(r0) | (bf16_rne(r1) << 16);
    o[1] = bf16_rne(r2) | (bf16_rne(r3) << 16);
    o[2] = bf16_rne(r4) | (bf16_rne(r5) << 16);
    o[3] = bf16_rne(r6) | (bf16_rne(r7) << 16);
    o[4] = bf16_rne(r8);
    o[5] = __float_as_uint(params[6 * c + 3]);
    o[6] = __float_as_uint(params[6 * c + 4]);
    o[7] = __float_as_uint(params[6 * c + 5]);
}

// ---------------------------------------------------------------------------
// Kernel 2: identical structure to the 91.7us R3 kernel (1024-pt tile,
// 36 KB LDS transpose arena, gathers after the first barrier). Only the
// camera record format changed: 32 B bf16-packed -> 2 dwordx4 gathers/pt
// and an L1-resident table.
// out layout (floats): [new_o: 3N][new_d: 3N][trans: 3N][R: 9N]
// ---------------------------------------------------------------------------
__launch_bounds__(256)
__global__ void cam_apply(const int* __restrict__ idx,
                          const float* __restrict__ of,
                          const float* __restrict__ df,
                          const uint4* __restrict__ cams8,
                          float* __restrict__ out,
                          long long N) {
    __shared__ float lds[9216];   // 36 KB arena
    const int tid = threadIdx.x;
    const long long tileBase = (long long)blockIdx.x * 1024;

    if (tileBase + 1024 <= N) {
        // ---- P1: stage o, d tiles (12 KB each), dense f32x4 loads ----
        const f32x4* o4 = (const f32x4*)(of + 3 * tileBase);   // 768 f32x4
        const f32x4* d4 = (const f32x4*)(df + 3 * tileBase);
        f32x4* A = (f32x4*)lds;              // o tile: floats [0, 3072)
        f32x4* B = (f32x4*)(lds + 3072);     // d tile: floats [3072, 6144)
#pragma unroll
        for (int j = 0; j < 3; ++j) A[tid + 256 * j] = o4[tid + 256 * j];
#pragma unroll
        for (int j = 0; j < 3; ++j) B[tid + 256 * j] = d4[tid + 256 * j];

        int id[4];
#pragma unroll
        for (int k = 0; k < 4; ++k) id[k] = idx[tileBase + tid + 256 * k];
        __syncthreads();

        // ---- P2: compute 4 points/thread (n = tid + 256k) ----
        float R[4][9], T[4][3], no[12], nd[12];
#pragma unroll
        for (int k = 0; k < 4; ++k) {
            int n = tid + 256 * k;
            float ox = lds[3 * n + 0], oy = lds[3 * n + 1], oz = lds[3 * n + 2];
            float dx = lds[3072 + 3 * n + 0], dy = lds[3072 + 3 * n + 1],
                  dz = lds[3072 + 3 * n + 2];
            const uint4* cp = cams8 + 2 * (long long)id[k];
            uint4 q0 = cp[0], q1 = cp[1];
            R[k][0] = bf_lo(q0.x); R[k][1] = bf_hi(q0.x);
            R[k][2] = bf_lo(q0.y); R[k][3] = bf_hi(q0.y);
            R[k][4] = bf_lo(q0.z); R[k][5] = bf_hi(q0.z);
            R[k][6] = bf_lo(q0.w); R[k][7] = bf_hi(q0.w);
            R[k][8] = bf_lo(q1.x);
            T[k][0] = __uint_as_float(q1.y);
            T[k][1] = __uint_as_float(q1.z);
            T[k][2] = __uint_as_float(q1.w);

            no[3 * k + 0] = R[k][0] * ox + R[k][1] * oy + R[k][2] * oz + T[k][0];
            no[3 * k + 1] = R[k][3] * ox + R[k][4] * oy + R[k][5] * oz + T[k][1];
            no[3 * k + 2] = R[k][6] * ox + R[k][7] * oy + R[k][8] * oz + T[k][2];

            nd[3 * k + 0] = R[k][0] * dx + R[k][1] * dy + R[k][2] * dz;
            nd[3 * k + 1] = R[k][3] * dx + R[k][4] * dy + R[k][5] * dz;
            nd[3 * k + 2] = R[k][6] * dx + R[k][7] * dy + R[k][8] * dz;
        }
        __syncthreads();   // all o/d reads done; arena reusable

        // ---- P3: write no/nd/tr to arena (stride-3, conflict-free) ----
#pragma unroll
        for (int k = 0; k < 4; ++k) {
            int n = tid + 256 * k;
            lds[3 * n + 0] = no[3 * k + 0];
            lds[3 * n + 1] = no[3 * k + 1];
            lds[3 * n + 2] = no[3 * k + 2];
            lds[3072 + 3 * n + 0] = nd[3 * k + 0];
            lds[3072 + 3 * n + 1] = nd[3 * k + 1];
            lds[3072 + 3 * n + 2] = nd[3 * k + 2];
            lds[6144 + 3 * n + 0] = T[k][0];
            lds[6144 + 3 * n + 1] = T[k][1];
            lds[6144 + 3 * n + 2] = T[k][2];
        }
        __syncthreads();

        // ---- P4: dense flush of new_o, new_d, trans ----
        const f32x4* src = (const f32x4*)lds;
        f32x4* g0 = (f32x4*)(out + 3 * tileBase);
        f32x4* g1 = (f32x4*)(out + 3 * N + 3 * tileBase);
        f32x4* g2 = (f32x4*)(out + 6 * N + 3 * tileBase);
#pragma unroll
        for (int j = 0; j < 3; ++j) g0[tid + 256 * j] = src[tid + 256 * j];
#pragma unroll
        for (int j = 0; j < 3; ++j) g1[tid + 256 * j] = src[768 + tid + 256 * j];
#pragma unroll
        for (int j = 0; j < 3; ++j) g2[tid + 256 * j] = src[1536 + tid + 256 * j];
        __syncthreads();   // flush reads done; arena reusable

        // ---- P5: R tile (9216 floats = whole arena), stride-9 ----
#pragma unroll
        for (int k = 0; k < 4; ++k) {
            int n = tid + 256 * k;
#pragma unroll
            for (int j = 0; j < 9; ++j) lds[9 * n + j] = R[k][j];
        }
        __syncthreads();

        f32x4* g3 = (f32x4*)(out + 9 * N + 9 * tileBase);
#pragma unroll
        for (int j = 0; j < 9; ++j) g3[tid + 256 * j] = src[tid + 256 * j];
    } else {
        // ---- tail tile: scalar guarded path ----
        for (int k = 0; k < 4; ++k) {
            long long n = tileBase + tid + 256 * k;
            if (n >= N) continue;
            int cid = idx[n];
            const uint4* cp = cams8 + 2 * (long long)cid;
            uint4 q0 = cp[0], q1 = cp[1];
            float Rv[9] = {bf_lo(q0.x), bf_hi(q0.x), bf_lo(q0.y), bf_hi(q0.y),
                           bf_lo(q0.z), bf_hi(q0.z), bf_lo(q0.w), bf_hi(q0.w),
                           bf_lo(q1.x)};
            float t0 = __uint_as_float(q1.y), t1 = __uint_as_float(q1.z),
                  t2 = __uint_as_float(q1.w);
            float ox = of[3 * n + 0], oy = of[3 * n + 1], oz = of[3 * n + 2];
            float dx = df[3 * n + 0], dy = df[3 * n + 1], dz = df[3 * n + 2];

            out[3 * n + 0] = Rv[0] * ox + Rv[1] * oy + Rv[2] * oz + t0;
            out[3 * n + 1] = Rv[3] * ox + Rv[4] * oy + Rv[5] * oz + t1;
            out[3 * n + 2] = Rv[6] * ox + Rv[7] * oy + Rv[8] * oz + t2;

            out[3 * N + 3 * n + 0] = Rv[0] * dx + Rv[1] * dy + Rv[2] * dz;
            out[3 * N + 3 * n + 1] = Rv[3] * dx + Rv[4] * dy + Rv[5] * dz;
            out[3 * N + 3 * n + 2] = Rv[6] * dx + Rv[7] * dy + Rv[8] * dz;

            out[6 * N + 3 * n + 0] = t0;
            out[6 * N + 3 * n + 1] = t1;
            out[6 * N + 3 * n + 2] = t2;

            for (int j = 0; j < 9; ++j) out[9 * N + 9 * n + j] = Rv[j];
        }
    }
}

extern "C" void kernel_launch(void* const* d_in, const int* in_sizes, int n_in,
                              void* d_out, int out_size, void* d_ws, size_t ws_size,
                              hipStream_t stream) {
    const float* params = (const float*)d_in[0];
    const int*   idx    = (const int*)d_in[1];
    const float* o      = (const float*)d_in[2];
    const float* d      = (const float*)d_in[3];
    float*       out    = (float*)d_out;
    unsigned*    cams   = (unsigned*)d_ws;   // size*8 u32 (32 KB for size=1000)

    int size = in_sizes[0] / 6;
    long long N = (long long)in_sizes[2] / 3;

    cam_precompute<<<(size + 255) / 256, 256, 0, stream>>>(params, cams, size);

    int blocks = (int)((N + 1023) / 1024);
    cam_apply<<<blocks, 256, 0, stream>>>(idx, o, d, (const uint4*)cams,
                                          out, N);
}